// Round 1
// baseline (2565.014 us; speedup 1.0000x reference)
//
#include <hip/hip_runtime.h>

#define Bn 32
#define Tn 512
#define Dn 512
#define Vn 512

typedef _Float16 h1;
typedef _Float16 h2 __attribute__((ext_vector_type(2)));

// ---- 8 f16 pairs MAC into f32 acc (compiles to v_fma_mix on gfx950) ----
__device__ __forceinline__ float dot8acc(uint4 a, uint4 b, float acc) {
  union { uint4 u; h2 h[4]; } A, Bv;
  A.u = a; Bv.u = b;
#pragma unroll
  for (int p = 0; p < 4; ++p) {
    acc = fmaf((float)A.h[p][0], (float)Bv.h[p][0], acc);
    acc = fmaf((float)A.h[p][1], (float)Bv.h[p][1], acc);
  }
  return acc;
}

// ---- global max-min of transitions (rigorous pruning radius) ----
__global__ __launch_bounds__(1024) void crf_minmax(const float* __restrict__ trans,
                                                   float* __restrict__ Rout) {
  int tid = threadIdx.x;
  float mn = 3e38f, mx = -3e38f;
  for (int i = tid; i < Vn * Vn; i += 1024) {
    float v = trans[i];
    mn = fminf(mn, v); mx = fmaxf(mx, v);
  }
#pragma unroll
  for (int off = 1; off < 64; off <<= 1) {
    mn = fminf(mn, __shfl_xor(mn, off));
    mx = fmaxf(mx, __shfl_xor(mx, off));
  }
  __shared__ float smn[16], smx[16];
  int w = tid >> 6;
  if ((tid & 63) == 0) { smn[w] = mn; smx[w] = mx; }
  __syncthreads();
  if (tid == 0) {
    for (int i = 1; i < 16; ++i) { mn = fminf(mn, smn[i]); mx = fmaxf(mx, smx[i]); }
    Rout[0] = mx - mn;
  }
}

// ---- E3[v,u] = exp(trans[u][v]) as f16, wave-coalesced permuted layout ----
// element index: (((v>>5)*32 + i)*64 + ((v&31)*2 + h))*8 + j  where u = h*256 + i*8 + j
__global__ __launch_bounds__(256) void crf_build_E(const float* __restrict__ trans,
                                                   h1* __restrict__ E3) {
  __shared__ float tl[64][65];
  int wg = blockIdx.x;
  int u0 = (wg >> 3) * 64, v0 = (wg & 7) * 64;
  int tid = threadIdx.x;
  int col = tid & 63, rbase = tid >> 6;
#pragma unroll
  for (int rr = 0; rr < 16; ++rr) {
    int row = rr * 4 + rbase;
    tl[row][col] = trans[(size_t)(u0 + row) * Vn + (v0 + col)];
  }
  __syncthreads();
#pragma unroll
  for (int p = 0; p < 16; ++p) {
    int l = tid + 256 * p;
    int vloc = l >> 6, uloc = l & 63;
    int v = v0 + vloc, u = u0 + uloc;
    float e = __expf(tl[uloc][vloc]);
    int h = u >> 8, rem = u & 255, ii = rem >> 3, j = rem & 7;
    int idx = ((((v >> 5) * 32 + ii) * 64) + ((v & 31) * 2 + h)) * 8 + j;
    E3[idx] = (h1)e;
  }
}

// ---- emissions = X(16384x512) * W^T(512x512), f32, 64x64 tile BK=16 ----
__global__ __launch_bounds__(256) void crf_gemm(const float* __restrict__ X,
                                                const float* __restrict__ Wt,
                                                float* __restrict__ C) {
  __shared__ float As[16][68];
  __shared__ float Bs[16][68];
  const int tid = threadIdx.x;
  const int m0 = (int)(blockIdx.x >> 3) * 64;
  const int v0 = (int)(blockIdx.x & 7) * 64;
  const int lr = tid >> 2;
  const int lk = (tid & 3) * 4;
  const int ty = tid >> 4, tx = tid & 15;
  float acc[4][4] = {};
  const float* xrow = X + (size_t)(m0 + lr) * Dn + lk;
  const float* wrow = Wt + (size_t)(v0 + lr) * Dn + lk;
  for (int k0 = 0; k0 < Dn; k0 += 16) {
    float4 av = *(const float4*)(xrow + k0);
    float4 bv = *(const float4*)(wrow + k0);
    __syncthreads();
    As[lk + 0][lr] = av.x; As[lk + 1][lr] = av.y; As[lk + 2][lr] = av.z; As[lk + 3][lr] = av.w;
    Bs[lk + 0][lr] = bv.x; Bs[lk + 1][lr] = bv.y; Bs[lk + 2][lr] = bv.z; Bs[lk + 3][lr] = bv.w;
    __syncthreads();
#pragma unroll
    for (int kk = 0; kk < 16; ++kk) {
      float4 a = *(const float4*)&As[kk][ty * 4];
      float4 b4 = *(const float4*)&Bs[kk][tx * 4];
      float a_[4] = {a.x, a.y, a.z, a.w};
      float b_[4] = {b4.x, b4.y, b4.z, b4.w};
#pragma unroll
      for (int j = 0; j < 4; ++j)
#pragma unroll
        for (int i = 0; i < 4; ++i)
          acc[j][i] = fmaf(a_[j], b_[i], acc[j][i]);
    }
  }
#pragma unroll
  for (int j = 0; j < 4; ++j) {
    float4 o; o.x = acc[j][0]; o.y = acc[j][1]; o.z = acc[j][2]; o.w = acc[j][3];
    *(float4*)(C + (size_t)(m0 + ty * 4 + j) * Vn + v0 + tx * 4) = o;
  }
}

// ---- fused scan: blocks 0..31 forward(logZ,loglik); 32..63 viterbi+backtrace ----
__global__ __launch_bounds__(1024) void crf_scan(
    const float* __restrict__ emis, const float* __restrict__ trans,
    const h1* __restrict__ E3, const float* __restrict__ Rp,
    const int* __restrict__ tgt, const unsigned char* __restrict__ pad,
    unsigned short* __restrict__ bps, float* __restrict__ out_ll,
    float* __restrict__ out_tok) {
  __shared__ __align__(16) float alpha[Vn];
  __shared__ __align__(16) h1 ph[Vn];
  __shared__ float wred[16];
  __shared__ float mshared;
  __shared__ __align__(16) float va[Vn];
  __shared__ unsigned short S[Vn];
  __shared__ int wcnt[8], wbase[8], scnt;
  __shared__ float wvals[16];
  __shared__ int widxs[16];
  __shared__ int lastS;
  __shared__ unsigned short tokens[Tn];
  __shared__ __align__(16) unsigned short bpbuf[32][Vn];

  const int tid = threadIdx.x;
  const int b = blockIdx.x & 31;
  const int role = blockIdx.x >> 5;
  const float* eb = emis + (size_t)b * Tn * Vn;
  const int w = tid >> 6;
  const int lane = tid & 63;

  if (role == 0) {
    // ================== FORWARD (logsumexp) ==================
    const int v = tid >> 1, h = tid & 1;
    float a0 = eb[v];
    if (h == 0) alpha[v] = a0;
    float r = a0;
#pragma unroll
    for (int off = 1; off < 64; off <<= 1) r = fmaxf(r, __shfl_xor(r, off));
    if (lane == 0) wred[w] = r;
    __syncthreads();
    if (tid == 0) {
      float mm = wred[0];
      for (int i = 1; i < 16; ++i) mm = fmaxf(mm, wred[i]);
      mshared = mm;
    }
    __syncthreads();
    float m = mshared;

    const uint4* Ep = (const uint4*)(E3 + (size_t)(v >> 5) * 16384) + ((v & 31) * 2 + h);
    const uint4* Pp = (const uint4*)ph + h * 32;

    for (int t = 1; t < Tn; ++t) {
      if (tid < 512) ph[tid] = (h1)__expf(alpha[tid] - m);
      __syncthreads();
      float acc = 0.f;
#pragma unroll 4
      for (int i = 0; i < 32; ++i) acc = dot8acc(Ep[i * 64], Pp[i], acc);
      float tot = acc + __shfl_xor(acc, 1);
      float emitv = eb[t * Vn + v];
      float nv = m + __logf(tot) + emitv;
      if (pad[b * Tn + t]) nv = alpha[v];
      float r2 = nv;
#pragma unroll
      for (int off = 1; off < 64; off <<= 1) r2 = fmaxf(r2, __shfl_xor(r2, off));
      if (lane == 0) wred[w] = r2;
      __syncthreads();
      if (h == 0) alpha[v] = nv;
      if (tid == 0) {
        float mm = wred[0];
        for (int i = 1; i < 16; ++i) mm = fmaxf(mm, wred[i]);
        mshared = mm;
      }
      __syncthreads();
      m = mshared;
    }

    // logZ
    float ex = (tid < 512) ? __expf(alpha[tid] - m) : 0.f;
#pragma unroll
    for (int off = 1; off < 64; off <<= 1) ex += __shfl_xor(ex, off);
    if (lane == 0) wred[w] = ex;
    __syncthreads();
    float logZ = 0.f;
    if (tid == 0) {
      float s = 0.f;
      for (int i = 0; i < 16; ++i) s += wred[i];
      logZ = m + __logf(s);
    }
    __syncthreads();
    // gold score
    float sc = 0.f;
    if (tid < 512) {
      int t = tid;
      int tg = tgt[b * Tn + t];
      float mt = pad[b * Tn + t] ? 0.f : 1.f;
      sc = eb[t * Vn + tg] * mt;
      if (t < Tn - 1) {
        int tg1 = tgt[b * Tn + t + 1];
        float mt1 = pad[b * Tn + t + 1] ? 0.f : 1.f;
        sc += trans[(size_t)tg * Vn + tg1] * mt * mt1;
      }
    }
#pragma unroll
    for (int off = 1; off < 64; off <<= 1) sc += __shfl_xor(sc, off);
    if (lane == 0) wred[w] = sc;
    __syncthreads();
    if (tid == 0) {
      float s = 0.f;
      for (int i = 0; i < 16; ++i) s += wred[i];
      out_ll[b] = s - logZ;
    }
  } else {
    // ================== VITERBI ==================
    float R = Rp[0] * 1.000001f + 1e-4f;  // safe overestimate of maxT-minT
    if (tid < 512) va[tid] = eb[tid];
    float r = (tid < 512) ? eb[tid] : -3e38f;
#pragma unroll
    for (int off = 1; off < 64; off <<= 1) r = fmaxf(r, __shfl_xor(r, off));
    if (lane == 0) wvals[w] = r;
    __syncthreads();
    if (tid == 0) {
      float mm = wvals[0];
      for (int i = 1; i < 16; ++i) mm = fmaxf(mm, wvals[i]);
      mshared = mm;
    }
    __syncthreads();
    float A = mshared;

    for (int t = 1; t < Tn; ++t) {
      // candidates: va[u] >= A - R  (ascending u for first-index argmax semantics)
      float thr = A - R;
      bool pr = (tid < 512) && (va[tid] >= thr);
      unsigned long long mk = __ballot(pr);
      if (tid < 512 && lane == 0) wcnt[w] = (int)__popcll(mk);
      __syncthreads();
      if (tid == 0) {
        int run = 0;
        for (int i = 0; i < 8; ++i) { wbase[i] = run; run += wcnt[i]; }
        scnt = run;
      }
      __syncthreads();
      if (pr) {
        int pos = wbase[w] + (int)__popcll(mk & ((1ull << lane) - 1ull));
        S[pos] = (unsigned short)tid;
      }
      __syncthreads();
      int n = scnt;
      float nv = 0.f; int bp = 0;
      if (tid < 512) {
        float best = -3e38f; int arg = 0;
        for (int s = 0; s < n; ++s) {
          int u = S[s];
          float val = va[u] + trans[(size_t)u * Vn + tid];
          if (val > best) { best = val; arg = u; }
        }
        nv = best + eb[t * Vn + tid];
        bp = arg;
        if (pad[b * Tn + t]) { nv = va[tid]; bp = tid; }
        bps[((size_t)(t - 1) * Bn + b) * Vn + tid] = (unsigned short)bp;
      }
      float r2 = (tid < 512) ? nv : -3e38f;
#pragma unroll
      for (int off = 1; off < 64; off <<= 1) r2 = fmaxf(r2, __shfl_xor(r2, off));
      if (lane == 0) wvals[w] = r2;
      __syncthreads();
      if (tid < 512) va[tid] = nv;
      if (tid == 0) {
        float mm = wvals[0];
        for (int i = 1; i < 16; ++i) mm = fmaxf(mm, wvals[i]);
        mshared = mm;
      }
      __syncthreads();
      A = mshared;
    }

    // last = first-index argmax of final va
    float val = (tid < 512) ? va[tid] : -3e38f;
    int idx = (tid < 512) ? tid : (1 << 30);
#pragma unroll
    for (int off = 1; off < 64; off <<= 1) {
      float ov = __shfl_xor(val, off);
      int oi = __shfl_xor(idx, off);
      if (ov > val || (ov == val && oi < idx)) { val = ov; idx = oi; }
    }
    if (lane == 0) { wvals[w] = val; widxs[w] = idx; }
    __syncthreads();
    if (tid == 0) {
      float bv = wvals[0]; int bi = widxs[0];
      for (int i = 1; i < 16; ++i)
        if (wvals[i] > bv || (wvals[i] == bv && widxs[i] < bi)) { bv = wvals[i]; bi = widxs[i]; }
      lastS = bi;
    }
    __syncthreads();
    int tok = lastS;

    // backtrace: rows 510..0, 32-row LDS chunks
    for (int c = 15; c >= 0; --c) {
      int rhi = c * 32 + 31; if (rhi > 510) rhi = 510;
      int srow = tid >> 5, part = tid & 31;
      int row = c * 32 + srow;
      if (row <= 510) {
        const uint4* src = (const uint4*)(bps + ((size_t)row * Bn + b) * Vn);
        uint4* dst = (uint4*)&bpbuf[srow][0];
        dst[part * 2] = src[part * 2];
        dst[part * 2 + 1] = src[part * 2 + 1];
      }
      __syncthreads();
      if (tid == 0) {
        int tk = tok;
        for (int rr = rhi; rr >= c * 32; --rr) {
          tokens[rr + 1] = (unsigned short)tk;
          tk = bpbuf[rr - c * 32][tk];
        }
        tok = tk;
      }
      __syncthreads();
    }
    if (tid == 0) tokens[0] = (unsigned short)tok;
    __syncthreads();
    if (tid < 512) out_tok[b * Tn + tid] = (float)tokens[tid];
  }
}

extern "C" void kernel_launch(void* const* d_in, const int* in_sizes, int n_in,
                              void* d_out, int out_size, void* d_ws, size_t ws_size,
                              hipStream_t stream) {
  const float* x = (const float*)d_in[0];
  const float* w = (const float*)d_in[1];
  const float* trans = (const float*)d_in[2];
  const int* tgt = (const int*)d_in[3];
  const unsigned char* pad = (const unsigned char*)d_in[4];
  float* out = (float*)d_out;

  char* ws = (char*)d_ws;
  float* Rp = (float*)ws;                                   // 64 B
  h1* E3 = (h1*)(ws + 64);                                  // 512 KB
  unsigned short* bps = (unsigned short*)(ws + 64 + 524288);// ~16.4 MB

  float* emis = out;                 // (B,T,V)
  float* out_ll = out + 8388608;     // (B,)
  float* out_tok = out + 8388640;    // (B,T) as float

  hipLaunchKernelGGL(crf_minmax, dim3(1), dim3(1024), 0, stream, trans, Rp);
  hipLaunchKernelGGL(crf_build_E, dim3(64), dim3(256), 0, stream, trans, E3);
  hipLaunchKernelGGL(crf_gemm, dim3(2048), dim3(256), 0, stream, x, w, emis);
  hipLaunchKernelGGL(crf_scan, dim3(64), dim3(1024), 0, stream, emis, trans, E3, Rp,
                     tgt, pad, bps, out_ll, out_tok);
}

// Round 2
// 1964.824 us; speedup vs baseline: 1.3055x; 1.3055x over previous
//
#include <hip/hip_runtime.h>

#define Bn 32
#define Tn 512
#define Dn 512
#define Vn 512

typedef _Float16 h1;
typedef _Float16 h2 __attribute__((ext_vector_type(2)));

#if __has_builtin(__builtin_amdgcn_fdot2)
__device__ __forceinline__ float DOT2(h2 a, h2 b, float c) {
  return __builtin_amdgcn_fdot2(a, b, c, false);
}
#else
__device__ __forceinline__ float DOT2(h2 a, h2 b, float c) {
  return fmaf((float)a[0], (float)b[0], fmaf((float)a[1], (float)b[1], c));
}
#endif

__device__ __forceinline__ float max8lds(const float* p) {
  float4 a = *(const float4*)p;
  float4 b = *(const float4*)(p + 4);
  return fmaxf(fmaxf(fmaxf(a.x, a.y), fmaxf(a.z, a.w)),
               fmaxf(fmaxf(b.x, b.y), fmaxf(b.z, b.w)));
}

__device__ __forceinline__ float wavemax(float r) {
#pragma unroll
  for (int off = 1; off < 64; off <<= 1) r = fmaxf(r, __shfl_xor(r, off));
  return r;
}

// ---- global max-min of transitions (rigorous pruning radius) ----
__global__ __launch_bounds__(1024) void crf_minmax(const float* __restrict__ trans,
                                                   float* __restrict__ Rout) {
  int tid = threadIdx.x;
  float mn = 3e38f, mx = -3e38f;
  for (int i = tid; i < Vn * Vn; i += 1024) {
    float v = trans[i];
    mn = fminf(mn, v); mx = fmaxf(mx, v);
  }
#pragma unroll
  for (int off = 1; off < 64; off <<= 1) {
    mn = fminf(mn, __shfl_xor(mn, off));
    mx = fmaxf(mx, __shfl_xor(mx, off));
  }
  __shared__ float smn[16], smx[16];
  int w = tid >> 6;
  if ((tid & 63) == 0) { smn[w] = mn; smx[w] = mx; }
  __syncthreads();
  if (tid == 0) {
    for (int i = 1; i < 16; ++i) { mn = fminf(mn, smn[i]); mx = fmaxf(mx, smx[i]); }
    Rout[0] = mx - mn;
  }
}

// ---- E3[v][u] = exp(trans[u][v]) as f16, plain row-major [v*512+u] ----
__global__ __launch_bounds__(256) void crf_build_E(const float* __restrict__ trans,
                                                   h1* __restrict__ E3) {
  __shared__ float tl[64][65];
  int u0 = (int)(blockIdx.x >> 3) * 64, v0 = (int)(blockIdx.x & 7) * 64;
  int tid = threadIdx.x;
  int col = tid & 63, r0 = tid >> 6;
#pragma unroll
  for (int rr = 0; rr < 16; ++rr) {
    int row = rr * 4 + r0;
    tl[row][col] = trans[(size_t)(u0 + row) * Vn + (v0 + col)];
  }
  __syncthreads();
#pragma unroll
  for (int p = 0; p < 16; ++p) {
    int l = tid + 256 * p;
    int vloc = l >> 6, uloc = l & 63;
    E3[(size_t)(v0 + vloc) * Vn + (u0 + uloc)] = (h1)__expf(tl[uloc][vloc]);
  }
}

// ---- emissions = X(16384x512) * W^T(512x512), f32, 64x64 tile BK=16 ----
__global__ __launch_bounds__(256) void crf_gemm(const float* __restrict__ X,
                                                const float* __restrict__ Wt,
                                                float* __restrict__ C) {
  __shared__ float As[16][68];
  __shared__ float Bs[16][68];
  const int tid = threadIdx.x;
  const int m0 = (int)(blockIdx.x >> 3) * 64;
  const int v0 = (int)(blockIdx.x & 7) * 64;
  const int lr = tid >> 2;
  const int lk = (tid & 3) * 4;
  const int ty = tid >> 4, tx = tid & 15;
  float acc[4][4] = {};
  const float* xrow = X + (size_t)(m0 + lr) * Dn + lk;
  const float* wrow = Wt + (size_t)(v0 + lr) * Dn + lk;
  for (int k0 = 0; k0 < Dn; k0 += 16) {
    float4 av = *(const float4*)(xrow + k0);
    float4 bv = *(const float4*)(wrow + k0);
    __syncthreads();
    As[lk + 0][lr] = av.x; As[lk + 1][lr] = av.y; As[lk + 2][lr] = av.z; As[lk + 3][lr] = av.w;
    Bs[lk + 0][lr] = bv.x; Bs[lk + 1][lr] = bv.y; Bs[lk + 2][lr] = bv.z; Bs[lk + 3][lr] = bv.w;
    __syncthreads();
#pragma unroll
    for (int kk = 0; kk < 16; ++kk) {
      float4 a = *(const float4*)&As[kk][ty * 4];
      float4 b4 = *(const float4*)&Bs[kk][tx * 4];
      float a_[4] = {a.x, a.y, a.z, a.w};
      float b_[4] = {b4.x, b4.y, b4.z, b4.w};
#pragma unroll
      for (int j = 0; j < 4; ++j)
#pragma unroll
        for (int i = 0; i < 4; ++i)
          acc[j][i] = fmaf(a_[j], b_[i], acc[j][i]);
    }
  }
#pragma unroll
  for (int j = 0; j < 4; ++j) {
    float4 o; o.x = acc[j][0]; o.y = acc[j][1]; o.z = acc[j][2]; o.w = acc[j][3];
    *(float4*)(C + (size_t)(m0 + ty * 4 + j) * Vn + v0 + tx * 4) = o;
  }
}

// ---- fused scan: blocks 0..31 forward(logZ,loglik); 32..63 viterbi+backtrace ----
// 512 threads. Forward: thread (cg=tid>>2, h=tid&3) holds E columns cg*4+0..3,
// K-quarter h (128 rows) in 256 VGPRs; per-step p broadcast via padded LDS.
__global__ __launch_bounds__(512) void crf_scan(
    const float* __restrict__ emis, const float* __restrict__ trans,
    const h1* __restrict__ E3, const float* __restrict__ Rp,
    const int* __restrict__ tgt, const unsigned char* __restrict__ pad,
    unsigned short* __restrict__ bps, float* __restrict__ out_ll,
    float* __restrict__ out_tok) {
  __shared__ __align__(16) h1 ph[4 * 136];       // 4 quarters, 8-f16 pad each (bank shift 4)
  __shared__ __align__(16) float wred[8];
  __shared__ __align__(16) float wred2[8];
  __shared__ __align__(16) float va[Vn];
  __shared__ unsigned short S[Vn];
  __shared__ __align__(16) int wcnt[8];
  __shared__ __align__(16) float wvals[8];
  __shared__ int widxs[8];
  __shared__ int lastS;
  __shared__ unsigned short tokens[Tn];
  __shared__ __align__(16) unsigned short bpbuf[32][Vn];

  const int tid = threadIdx.x;
  const int b = blockIdx.x & 31;
  const int role = blockIdx.x >> 5;
  const float* eb = emis + (size_t)b * Tn * Vn;
  const int w = tid >> 6;
  const int lane = tid & 63;

  if (role == 0) {
    // ================== FORWARD (logsumexp) ==================
    const int h = tid & 3, cg = tid >> 2;
    union EU { uint4 u[16]; h2 hh[64]; };
    EU E4[4];
    {
      const uint4* E3v = (const uint4*)E3;
#pragma unroll
      for (int j = 0; j < 4; ++j) {
        int base = (cg * 4 + j) * 64 + h * 16;  // uint4 index
#pragma unroll
        for (int i = 0; i < 16; ++i) E4[j].u[i] = E3v[base + i];
      }
    }
    float alphaR = eb[tid];
    {
      float r = wavemax(alphaR);
      if (lane == 0) wred[w] = r;
    }
    __syncthreads();

    for (int t = 1; t < Tn; ++t) {
      float m = max8lds(wred);
      float p = __expf(alphaR - m);
      ph[(tid >> 7) * 136 + (tid & 127)] = (h1)p;
      __syncthreads();
      float a0 = 0.f, a1 = 0.f, a2 = 0.f, a3 = 0.f;
      const uint4* Pp = (const uint4*)(ph + h * 136);
#pragma unroll
      for (int i = 0; i < 16; ++i) {
        union { uint4 u; h2 hh[4]; } P;
        P.u = Pp[i];
#pragma unroll
        for (int q = 0; q < 4; ++q) {
          a0 = DOT2(E4[0].hh[i * 4 + q], P.hh[q], a0);
          a1 = DOT2(E4[1].hh[i * 4 + q], P.hh[q], a1);
          a2 = DOT2(E4[2].hh[i * 4 + q], P.hh[q], a2);
          a3 = DOT2(E4[3].hh[i * 4 + q], P.hh[q], a3);
        }
      }
      // sum over the 4 h-lanes of each cg group
      a0 += __shfl_xor(a0, 1); a0 += __shfl_xor(a0, 2);
      a1 += __shfl_xor(a1, 1); a1 += __shfl_xor(a1, 2);
      a2 += __shfl_xor(a2, 1); a2 += __shfl_xor(a2, 2);
      a3 += __shfl_xor(a3, 1); a3 += __shfl_xor(a3, 2);
      float tot = (h == 0) ? a0 : (h == 1) ? a1 : (h == 2) ? a2 : a3;
      float nv = m + __logf(tot) + eb[(size_t)t * Vn + tid];
      if (pad[b * Tn + t]) nv = alphaR;
      alphaR = nv;
      float r2 = wavemax(nv);
      if (lane == 0) wred[w] = r2;
      __syncthreads();
    }

    // logZ
    float m = max8lds(wred);
    float ex = __expf(alphaR - m);
    __syncthreads();
#pragma unroll
    for (int off = 1; off < 64; off <<= 1) ex += __shfl_xor(ex, off);
    if (lane == 0) wred[w] = ex;
    // gold score (thread t = tid)
    float sc;
    {
      int t = tid;
      int tg = tgt[b * Tn + t];
      float mt = pad[b * Tn + t] ? 0.f : 1.f;
      sc = eb[(size_t)t * Vn + tg] * mt;
      if (t < Tn - 1) {
        int tg1 = tgt[b * Tn + t + 1];
        float mt1 = pad[b * Tn + t + 1] ? 0.f : 1.f;
        sc += trans[(size_t)tg * Vn + tg1] * mt * mt1;
      }
    }
#pragma unroll
    for (int off = 1; off < 64; off <<= 1) sc += __shfl_xor(sc, off);
    if (lane == 0) wred2[w] = sc;
    __syncthreads();
    if (tid == 0) {
      float s = 0.f, g = 0.f;
      for (int i = 0; i < 8; ++i) { s += wred[i]; g += wred2[i]; }
      out_ll[b] = g - (m + __logf(s));
    }
  } else {
    // ================== VITERBI ==================
    float R = Rp[0] * 1.000001f + 1e-4f;
    float vaR = eb[tid];
    va[tid] = vaR;
    {
      float r = wavemax(vaR);
      if (lane == 0) wvals[w] = r;
    }
    __syncthreads();
    float thr = max8lds(wvals) - R;

    for (int t = 1; t < Tn; ++t) {
      bool pr = (vaR >= thr);
      unsigned long long mk = __ballot(pr);
      if (lane == 0) wcnt[w] = (int)__popcll(mk);
      __syncthreads();
      int base = 0, n = 0;
#pragma unroll
      for (int i = 0; i < 8; ++i) {
        int c = wcnt[i];
        if (i < w) base += c;
        n += c;
      }
      if (pr) S[base + (int)__popcll(mk & ((1ull << lane) - 1ull))] = (unsigned short)tid;
      __syncthreads();
      float best = -3e38f; int arg = 0;
      for (int s = 0; s < n; ++s) {
        int u = S[s];
        float val = va[u] + trans[(size_t)u * Vn + tid];
        if (val > best) { best = val; arg = u; }
      }
      float nv = best + eb[(size_t)t * Vn + tid];
      int bp = arg;
      if (pad[b * Tn + t]) { nv = vaR; bp = tid; }
      bps[((size_t)(t - 1) * Bn + b) * Vn + tid] = (unsigned short)bp;
      float r2 = wavemax(nv);
      if (lane == 0) wvals[w] = r2;
      va[tid] = nv;
      vaR = nv;
      __syncthreads();
      thr = max8lds(wvals) - R;
    }

    // last = first-index argmax of final va
    {
      float val = vaR;
      int idx = tid;
#pragma unroll
      for (int off = 1; off < 64; off <<= 1) {
        float ov = __shfl_xor(val, off);
        int oi = __shfl_xor(idx, off);
        if (ov > val || (ov == val && oi < idx)) { val = ov; idx = oi; }
      }
      if (lane == 0) { wvals[w] = val; widxs[w] = idx; }
    }
    __syncthreads();
    if (tid == 0) {
      float bv = wvals[0]; int bi = widxs[0];
      for (int i = 1; i < 8; ++i)
        if (wvals[i] > bv || (wvals[i] == bv && widxs[i] < bi)) { bv = wvals[i]; bi = widxs[i]; }
      lastS = bi;
    }
    __syncthreads();
    int tok = lastS;

    // backtrace: rows 510..0, 32-row LDS chunks
    for (int c = 15; c >= 0; --c) {
      int rhi = c * 32 + 31; if (rhi > 510) rhi = 510;
      int srow = tid >> 4, part = tid & 15;
      int row = c * 32 + srow;
      if (row <= 510) {
        const uint4* src = (const uint4*)(bps + ((size_t)row * Bn + b) * Vn);
        uint4* dst = (uint4*)&bpbuf[srow][0];
#pragma unroll
        for (int q = 0; q < 4; ++q) dst[part * 4 + q] = src[part * 4 + q];
      }
      __syncthreads();
      if (tid == 0) {
        int tk = tok;
        for (int rr = rhi; rr >= c * 32; --rr) {
          tokens[rr + 1] = (unsigned short)tk;
          tk = bpbuf[rr - c * 32][tk];
        }
        tok = tk;
      }
      __syncthreads();
    }
    if (tid == 0) tokens[0] = (unsigned short)tok;
    __syncthreads();
    out_tok[b * Tn + tid] = (float)tokens[tid];
  }
}

extern "C" void kernel_launch(void* const* d_in, const int* in_sizes, int n_in,
                              void* d_out, int out_size, void* d_ws, size_t ws_size,
                              hipStream_t stream) {
  const float* x = (const float*)d_in[0];
  const float* w = (const float*)d_in[1];
  const float* trans = (const float*)d_in[2];
  const int* tgt = (const int*)d_in[3];
  const unsigned char* pad = (const unsigned char*)d_in[4];
  float* out = (float*)d_out;

  char* ws = (char*)d_ws;
  float* Rp = (float*)ws;                                    // 64 B
  h1* E3 = (h1*)(ws + 64);                                   // 512 KB
  unsigned short* bps = (unsigned short*)(ws + 64 + 524288); // ~16.7 MB

  float* emis = out;                 // (B,T,V)
  float* out_ll = out + 8388608;     // (B,)
  float* out_tok = out + 8388640;    // (B,T) as float

  hipLaunchKernelGGL(crf_minmax, dim3(1), dim3(1024), 0, stream, trans, Rp);
  hipLaunchKernelGGL(crf_build_E, dim3(64), dim3(256), 0, stream, trans, E3);
  hipLaunchKernelGGL(crf_gemm, dim3(2048), dim3(256), 0, stream, x, w, emis);
  hipLaunchKernelGGL(crf_scan, dim3(64), dim3(512), 0, stream, emis, trans, E3, Rp,
                     tgt, pad, bps, out_ll, out_tok);
}

// Round 3
// 1140.757 us; speedup vs baseline: 2.2485x; 1.7224x over previous
//
#include <hip/hip_runtime.h>

#define Bn 32
#define Tn 512
#define Dn 512
#define Vn 512

typedef _Float16 h1;
typedef _Float16 h2 __attribute__((ext_vector_type(2)));

#if __has_builtin(__builtin_amdgcn_fdot2)
__device__ __forceinline__ float DOT2(h2 a, h2 b, float c) {
  return __builtin_amdgcn_fdot2(a, b, c, false);
}
#else
__device__ __forceinline__ float DOT2(h2 a, h2 b, float c) {
  return fmaf((float)a[0], (float)b[0], fmaf((float)a[1], (float)b[1], c));
}
#endif

__device__ __forceinline__ float max8lds(const float* p) {
  float4 a = *(const float4*)p;
  float4 b = *(const float4*)(p + 4);
  return fmaxf(fmaxf(fmaxf(a.x, a.y), fmaxf(a.z, a.w)),
               fmaxf(fmaxf(b.x, b.y), fmaxf(b.z, b.w)));
}

__device__ __forceinline__ float wavemax(float r) {
#pragma unroll
  for (int off = 1; off < 64; off <<= 1) r = fmaxf(r, __shfl_xor(r, off));
  return r;
}

// ---- global max-min of transitions (rigorous pruning radius) ----
__global__ __launch_bounds__(1024) void crf_minmax(const float* __restrict__ trans,
                                                   float* __restrict__ Rout) {
  int tid = threadIdx.x;
  float mn = 3e38f, mx = -3e38f;
  for (int i = tid; i < Vn * Vn; i += 1024) {
    float v = trans[i];
    mn = fminf(mn, v); mx = fmaxf(mx, v);
  }
#pragma unroll
  for (int off = 1; off < 64; off <<= 1) {
    mn = fminf(mn, __shfl_xor(mn, off));
    mx = fmaxf(mx, __shfl_xor(mx, off));
  }
  __shared__ float smn[16], smx[16];
  int w = tid >> 6;
  if ((tid & 63) == 0) { smn[w] = mn; smx[w] = mx; }
  __syncthreads();
  if (tid == 0) {
    for (int i = 1; i < 16; ++i) { mn = fminf(mn, smn[i]); mx = fmaxf(mx, smx[i]); }
    Rout[0] = mx - mn;
  }
}

// ---- E3[v][u] = exp(trans[u][v]) as f16, plain row-major [v*512+u] ----
__global__ __launch_bounds__(256) void crf_build_E(const float* __restrict__ trans,
                                                   h1* __restrict__ E3) {
  __shared__ float tl[64][65];
  int u0 = (int)(blockIdx.x >> 3) * 64, v0 = (int)(blockIdx.x & 7) * 64;
  int tid = threadIdx.x;
  int col = tid & 63, r0 = tid >> 6;
#pragma unroll
  for (int rr = 0; rr < 16; ++rr) {
    int row = rr * 4 + r0;
    tl[row][col] = trans[(size_t)(u0 + row) * Vn + (v0 + col)];
  }
  __syncthreads();
#pragma unroll
  for (int p = 0; p < 16; ++p) {
    int l = tid + 256 * p;
    int vloc = l >> 6, uloc = l & 63;
    E3[(size_t)(v0 + vloc) * Vn + (u0 + uloc)] = (h1)__expf(tl[uloc][vloc]);
  }
}

// ---- emissions = X(16384x512) * W^T(512x512), f32, 64x64 tile BK=16 ----
__global__ __launch_bounds__(256) void crf_gemm(const float* __restrict__ X,
                                                const float* __restrict__ Wt,
                                                float* __restrict__ C) {
  __shared__ float As[16][68];
  __shared__ float Bs[16][68];
  const int tid = threadIdx.x;
  const int m0 = (int)(blockIdx.x >> 3) * 64;
  const int v0 = (int)(blockIdx.x & 7) * 64;
  const int lr = tid >> 2;
  const int lk = (tid & 3) * 4;
  const int ty = tid >> 4, tx = tid & 15;
  float acc[4][4] = {};
  const float* xrow = X + (size_t)(m0 + lr) * Dn + lk;
  const float* wrow = Wt + (size_t)(v0 + lr) * Dn + lk;
  for (int k0 = 0; k0 < Dn; k0 += 16) {
    float4 av = *(const float4*)(xrow + k0);
    float4 bv = *(const float4*)(wrow + k0);
    __syncthreads();
    As[lk + 0][lr] = av.x; As[lk + 1][lr] = av.y; As[lk + 2][lr] = av.z; As[lk + 3][lr] = av.w;
    Bs[lk + 0][lr] = bv.x; Bs[lk + 1][lr] = bv.y; Bs[lk + 2][lr] = bv.z; Bs[lk + 3][lr] = bv.w;
    __syncthreads();
#pragma unroll
    for (int kk = 0; kk < 16; ++kk) {
      float4 a = *(const float4*)&As[kk][ty * 4];
      float4 b4 = *(const float4*)&Bs[kk][tx * 4];
      float a_[4] = {a.x, a.y, a.z, a.w};
      float b_[4] = {b4.x, b4.y, b4.z, b4.w};
#pragma unroll
      for (int j = 0; j < 4; ++j)
#pragma unroll
        for (int i = 0; i < 4; ++i)
          acc[j][i] = fmaf(a_[j], b_[i], acc[j][i]);
    }
  }
#pragma unroll
  for (int j = 0; j < 4; ++j) {
    float4 o; o.x = acc[j][0]; o.y = acc[j][1]; o.z = acc[j][2]; o.w = acc[j][3];
    *(float4*)(C + (size_t)(m0 + ty * 4 + j) * Vn + v0 + tx * 4) = o;
  }
}

// ---- shared-memory union: forward vs viterbi roles ----
union SM {
  struct {
    uint4 EL[512 * 16];                       // 128 KB streamed part of E
    float wred[8];
    float wred2[8];
    unsigned char padsh[Tn];
    __align__(16) h1 ph[4 * 136];             // padded p broadcast buffer
  } f;
  struct {
    __align__(16) float va2[2][Vn];
    __align__(16) unsigned short bpbuf[32][Vn];
    unsigned short tokens[Tn];
    unsigned long long m8[8];
    __align__(16) float wvals[8];
    int widxs[8];
    unsigned char padsh[Tn];
    int lastS;
  } v;
};

// ---- fused scan: blocks 0..31 forward(logZ,loglik); 32..63 viterbi+backtrace ----
// Forward: thread (cg=tid>>2, h=tid&3) owns E cols cg*4+0..3, K-quarter h.
// Per column: 16 uint4 of f16; first 12 in VGPRs (48 total = 192 regs),
// last 4 streamed from LDS (16 ds_read_b128/step, wave-contiguous layout).
__global__ __launch_bounds__(512, 2) void crf_scan(
    const float* __restrict__ emis, const float* __restrict__ trans,
    const h1* __restrict__ E3, const float* __restrict__ Rp,
    const int* __restrict__ tgt, const unsigned char* __restrict__ pad,
    unsigned short* __restrict__ bps, float* __restrict__ out_ll,
    float* __restrict__ out_tok) {
  __shared__ SM sm;

  const int tid = threadIdx.x;
  const int b = blockIdx.x & 31;
  const int role = blockIdx.x >> 5;
  const float* eb = emis + (size_t)b * Tn * Vn;
  const int w = tid >> 6;
  const int lane = tid & 63;

  if (role == 0) {
    // ================== FORWARD (logsumexp) ==================
    const int h = tid & 3, cg = tid >> 2;
    const uint4* E3v = (const uint4*)E3;
    uint4 ER[48];
#pragma unroll
    for (int j = 0; j < 4; ++j)
#pragma unroll
      for (int i = 0; i < 12; ++i)
        ER[j * 12 + i] = E3v[(size_t)(cg * 4 + j) * 64 + h * 16 + i];
#pragma unroll
    for (int c = 0; c < 16; ++c) {
      int j = c >> 2, qq = c & 3;
      sm.f.EL[((w * 16 + c) << 6) + lane] =
          E3v[(size_t)(cg * 4 + j) * 64 + h * 16 + 12 + qq];
    }
    sm.f.padsh[tid] = pad[b * Tn + tid];
    float alphaR = eb[tid];
    float ecur = eb[Vn + tid];
    {
      float r = wavemax(alphaR);
      if (lane == 0) sm.f.wred[w] = r;
    }
    __syncthreads();

    for (int t = 1; t < Tn; ++t) {
      // region 1: rescale + broadcast p
      float m = max8lds(sm.f.wred);
      float p = __expf(alphaR - m);
      sm.f.ph[(tid >> 7) * 136 + (tid & 127)] = (h1)p;
      __syncthreads();  // A
      // region 2: dot + update
      float enext = (t + 1 < Tn) ? eb[(size_t)(t + 1) * Vn + tid] : 0.f;
      float a0 = 0.f, a1 = 0.f, a2 = 0.f, a3 = 0.f;
      const uint4* Pp = (const uint4*)(sm.f.ph + h * 136);
#pragma unroll
      for (int i = 0; i < 12; ++i) {
        union { uint4 u; h2 hh[4]; } P; P.u = Pp[i];
        union { uint4 u; h2 hh[4]; } e0, e1, e2, e3;
        e0.u = ER[0 * 12 + i]; e1.u = ER[1 * 12 + i];
        e2.u = ER[2 * 12 + i]; e3.u = ER[3 * 12 + i];
#pragma unroll
        for (int q = 0; q < 4; ++q) {
          a0 = DOT2(e0.hh[q], P.hh[q], a0);
          a1 = DOT2(e1.hh[q], P.hh[q], a1);
          a2 = DOT2(e2.hh[q], P.hh[q], a2);
          a3 = DOT2(e3.hh[q], P.hh[q], a3);
        }
      }
#pragma unroll
      for (int c = 0; c < 4; ++c) {
        union { uint4 u; h2 hh[4]; } P; P.u = Pp[12 + c];
        union { uint4 u; h2 hh[4]; } e0, e1, e2, e3;
        e0.u = sm.f.EL[((w * 16 + 0 + c) << 6) + lane];
        e1.u = sm.f.EL[((w * 16 + 4 + c) << 6) + lane];
        e2.u = sm.f.EL[((w * 16 + 8 + c) << 6) + lane];
        e3.u = sm.f.EL[((w * 16 + 12 + c) << 6) + lane];
#pragma unroll
        for (int q = 0; q < 4; ++q) {
          a0 = DOT2(e0.hh[q], P.hh[q], a0);
          a1 = DOT2(e1.hh[q], P.hh[q], a1);
          a2 = DOT2(e2.hh[q], P.hh[q], a2);
          a3 = DOT2(e3.hh[q], P.hh[q], a3);
        }
      }
      a0 += __shfl_xor(a0, 1); a0 += __shfl_xor(a0, 2);
      a1 += __shfl_xor(a1, 1); a1 += __shfl_xor(a1, 2);
      a2 += __shfl_xor(a2, 1); a2 += __shfl_xor(a2, 2);
      a3 += __shfl_xor(a3, 1); a3 += __shfl_xor(a3, 2);
      float tot = (h == 0) ? a0 : (h == 1) ? a1 : (h == 2) ? a2 : a3;
      float nv = m + __logf(tot) + ecur;
      if (sm.f.padsh[t]) nv = alphaR;
      alphaR = nv; ecur = enext;
      float r2 = wavemax(nv);
      if (lane == 0) sm.f.wred[w] = r2;
      __syncthreads();  // B
    }

    // logZ + gold score
    float m = max8lds(sm.f.wred);
    float ex = __expf(alphaR - m);
    __syncthreads();
#pragma unroll
    for (int off = 1; off < 64; off <<= 1) ex += __shfl_xor(ex, off);
    if (lane == 0) sm.f.wred[w] = ex;
    float sc;
    {
      int t = tid;
      int tg = tgt[b * Tn + t];
      float mt = sm.f.padsh[t] ? 0.f : 1.f;
      sc = eb[(size_t)t * Vn + tg] * mt;
      if (t < Tn - 1) {
        int tg1 = tgt[b * Tn + t + 1];
        float mt1 = sm.f.padsh[t + 1] ? 0.f : 1.f;
        sc += trans[(size_t)tg * Vn + tg1] * mt * mt1;
      }
    }
#pragma unroll
    for (int off = 1; off < 64; off <<= 1) sc += __shfl_xor(sc, off);
    if (lane == 0) sm.f.wred2[w] = sc;
    __syncthreads();
    if (tid == 0) {
      float s = 0.f, g = 0.f;
      for (int i = 0; i < 8; ++i) { s += sm.f.wred[i]; g += sm.f.wred2[i]; }
      out_ll[b] = g - (m + __logf(s));
    }
  } else {
    // ================== VITERBI ==================
    float R = Rp[0] * 1.000001f + 1e-4f;
    sm.v.padsh[tid] = pad[b * Tn + tid];
    float vaR = eb[tid];
    sm.v.va2[0][tid] = vaR;
    float ecur = eb[Vn + tid];
    {
      float r = wavemax(vaR);
      if (lane == 0) sm.v.wvals[w] = r;
    }
    __syncthreads();
    float thr = max8lds(sm.v.wvals) - R;

    for (int t = 1; t < Tn; ++t) {
      const int cur = t & 1, prev = cur ^ 1;
      unsigned long long mk = __ballot(vaR >= thr);
      if (lane == 0) sm.v.m8[w] = mk;
      __syncthreads();  // A
      float enext = (t + 1 < Tn) ? eb[(size_t)(t + 1) * Vn + tid] : 0.f;
      float best = -3e38f; int arg = 0;
      for (int w2 = 0; w2 < 8; ++w2) {
        unsigned long long mask = sm.v.m8[w2];
        while (mask) {
          int bb = __ffsll(mask) - 1;
          int u = (w2 << 6) + bb;
          float val = sm.v.va2[prev][u] + trans[(size_t)u * Vn + tid];
          if (val > best) { best = val; arg = u; }
          mask &= mask - 1;
        }
      }
      float nv = best + ecur; int bp = arg;
      if (sm.v.padsh[t]) { nv = vaR; bp = tid; }
      bps[((size_t)(t - 1) * Bn + b) * Vn + tid] = (unsigned short)bp;
      sm.v.va2[cur][tid] = nv;
      float r2 = wavemax(nv);
      if (lane == 0) sm.v.wvals[w] = r2;
      ecur = enext; vaR = nv;
      __syncthreads();  // B
      thr = max8lds(sm.v.wvals) - R;
    }

    // last = first-index argmax of final va
    {
      float val = vaR;
      int idx = tid;
#pragma unroll
      for (int off = 1; off < 64; off <<= 1) {
        float ov = __shfl_xor(val, off);
        int oi = __shfl_xor(idx, off);
        if (ov > val || (ov == val && oi < idx)) { val = ov; idx = oi; }
      }
      if (lane == 0) { sm.v.wvals[w] = val; sm.v.widxs[w] = idx; }
    }
    __syncthreads();
    if (tid == 0) {
      float bv = sm.v.wvals[0]; int bi = sm.v.widxs[0];
      for (int i = 1; i < 8; ++i)
        if (sm.v.wvals[i] > bv || (sm.v.wvals[i] == bv && sm.v.widxs[i] < bi)) {
          bv = sm.v.wvals[i]; bi = sm.v.widxs[i];
        }
      sm.v.lastS = bi;
    }
    __syncthreads();
    int tok = sm.v.lastS;

    // backtrace: rows 510..0, 32-row LDS chunks
    for (int c = 15; c >= 0; --c) {
      int rhi = c * 32 + 31; if (rhi > 510) rhi = 510;
      int srow = tid >> 4, part = tid & 15;
      int row = c * 32 + srow;
      if (row <= 510) {
        const uint4* src = (const uint4*)(bps + ((size_t)row * Bn + b) * Vn);
        uint4* dst = (uint4*)&sm.v.bpbuf[srow][0];
#pragma unroll
        for (int q = 0; q < 4; ++q) dst[part * 4 + q] = src[part * 4 + q];
      }
      __syncthreads();
      if (tid == 0) {
        int tk = tok;
        for (int rr = rhi; rr >= c * 32; --rr) {
          sm.v.tokens[rr + 1] = (unsigned short)tk;
          tk = sm.v.bpbuf[rr - c * 32][tk];
        }
        tok = tk;
      }
      __syncthreads();
    }
    if (tid == 0) sm.v.tokens[0] = (unsigned short)tok;
    __syncthreads();
    out_tok[b * Tn + tid] = (float)sm.v.tokens[tid];
  }
}

extern "C" void kernel_launch(void* const* d_in, const int* in_sizes, int n_in,
                              void* d_out, int out_size, void* d_ws, size_t ws_size,
                              hipStream_t stream) {
  const float* x = (const float*)d_in[0];
  const float* w = (const float*)d_in[1];
  const float* trans = (const float*)d_in[2];
  const int* tgt = (const int*)d_in[3];
  const unsigned char* pad = (const unsigned char*)d_in[4];
  float* out = (float*)d_out;

  char* ws = (char*)d_ws;
  float* Rp = (float*)ws;                                    // 64 B
  h1* E3 = (h1*)(ws + 64);                                   // 512 KB
  unsigned short* bps = (unsigned short*)(ws + 64 + 524288); // ~16.7 MB

  float* emis = out;                 // (B,T,V)
  float* out_ll = out + 8388608;     // (B,)
  float* out_tok = out + 8388640;    // (B,T) as float

  hipLaunchKernelGGL(crf_minmax, dim3(1), dim3(1024), 0, stream, trans, Rp);
  hipLaunchKernelGGL(crf_build_E, dim3(64), dim3(256), 0, stream, trans, E3);
  hipLaunchKernelGGL(crf_gemm, dim3(2048), dim3(256), 0, stream, x, w, emis);
  hipLaunchKernelGGL(crf_scan, dim3(64), dim3(512), 0, stream, emis, trans, E3, Rp,
                     tgt, pad, bps, out_ll, out_tok);
}